// Round 6
// baseline (389.208 us; speedup 1.0000x reference)
//
#include <hip/hip_runtime.h>
#include <cstdint>

// Int8 OPT attention block: B=2,T=2048,D=2048,H=32,HD=64
#define A_PROJ 3e-4f
#define A_QK   2e-5f
#define A_PV   1e-2f
#define A_OUT  1e-4f

#define NB 2
#define NT 2048
#define ND 2048
#define NH 32
#define NHD 64
#define NM (NB*NT)   // 4096 = B*T rows

typedef int v4i __attribute__((ext_vector_type(4)));

__device__ __forceinline__ int8_t sat8(float y) {
  float r = rintf(y);                      // half-to-even == np.round
  r = fminf(fmaxf(r, -128.f), 127.f);
  return (int8_t)(int)r;
}

// raw v_exp_f32: D = 2^x (device builtin; __exp2f collides with glibc macros)
__device__ __forceinline__ float exp2_fast(float x) {
  return __builtin_amdgcn_exp2f(x);
}

// async global->LDS, 16B/lane; LDS dest = wave-uniform base + lane*16
__device__ __forceinline__ void gl2lds16(const int8_t* g, int8_t* l) {
  __builtin_amdgcn_global_load_lds(
      (const __attribute__((address_space(1))) void*)g,
      (__attribute__((address_space(3))) void*)l, 16, 0, 0);
}

// ---------------- fused pack: int32 -> int8 for X + 4 weights ----------------
#define NWW (ND*ND/4)      // 1048576 words = 2^20
__global__ void pack_all(const int* __restrict__ X,
                         const int* __restrict__ W0, const int* __restrict__ W1,
                         const int* __restrict__ W2, const int* __restrict__ W3,
                         int8_t* __restrict__ dX, int8_t* __restrict__ dW0,
                         int8_t* __restrict__ dW1, int8_t* __restrict__ dW2,
                         int8_t* __restrict__ dW3) {
  int i = blockIdx.x * blockDim.x + threadIdx.x;
  const int nx = NM*ND/4;
  const int* src; int8_t* dst; int off;
  if (i < nx) { src = X; dst = dX; off = i; }
  else {
    int j = i - nx;
    int r = j >> 20;            // NWW = 2^20
    off = j & (NWW - 1);
    src = (r == 0) ? W0 : (r == 1) ? W1 : (r == 2) ? W2 : W3;
    dst = (r == 0) ? dW0 : (r == 1) ? dW1 : (r == 2) ? dW2 : dW3;
  }
  int4 v = ((const int4*)src)[off];
  uint32_t p = (uint32_t)(v.x & 255) | ((uint32_t)(v.y & 255) << 8) |
               ((uint32_t)(v.z & 255) << 16) | ((uint32_t)(v.w & 255) << 24);
  ((uint32_t*)dst)[off] = p;
}

// ---------------- QKV projection (B-direct restructured K-loop) ----------------
// A: gl2lds16 into double-buffered LDS (1 barrier per 64-k half, stage issued
//    into the idle buffer right after the barrier -> drain covers prev stage).
// B: direct global->VGPR b128 frags, prefetched one half ahead (bcur/bnxt) --
//    never part of the barrier vmcnt drain.
// z=0 -> Qh[b][h][t][hd], z=1 -> Kh[b][h][t][hd], z=2 -> Vt[b][h][hd][t]
__global__ __launch_bounds__(256, 3) void gemm_qkv(
    const int8_t* __restrict__ X,
    const int8_t* __restrict__ Wq, const int8_t* __restrict__ Wk, const int8_t* __restrict__ Wv,
    const int* __restrict__ bq, const int* __restrict__ bk, const int* __restrict__ bv,
    int8_t* __restrict__ Qh, int8_t* __restrict__ Kh, int8_t* __restrict__ Vt)
{
  __shared__ __align__(16) int8_t As[2][128][64];   // stored chunk = logical ^ ((row>>1)&3)
  const int z = blockIdx.z;
  const int8_t* W  = (z == 0) ? Wq : ((z == 1) ? Wk : Wv);
  const int* bias  = (z == 0) ? bq : ((z == 1) ? bk : bv);
  const int m0 = blockIdx.x * 128, n0 = blockIdx.y * 128;
  const int tid = threadIdx.x, lane = tid & 63, wave = tid >> 6;
  const int wm = wave >> 1, wn = wave & 1;
  const int l15 = lane & 15, quad = lane >> 4;

  const int srow = lane >> 2;                               // staging row within 16-block
  const int scol = (((lane & 3) ^ ((lane >> 3) & 3)) * 16); // swizzled logical chunk
  const int rqcol = (quad ^ ((l15 >> 1) & 3)) * 16;         // frag-read stored chunk

  // A staging sources (2 issues/wave: row blocks wave and wave+4)
  const int8_t* Xa0 = X + (size_t)(m0 + wave * 16 + srow) * ND + scol;
  const int8_t* Xa1 = X + (size_t)(m0 + (wave + 4) * 16 + srow) * ND + scol;
  int8_t* lA0[2] = { &As[0][wave * 16][0], &As[1][wave * 16][0] };
  int8_t* lA1[2] = { &As[0][(wave + 4) * 16][0], &As[1][(wave + 4) * 16][0] };

  // B frag source: row (n0 + wn*64 + nt*16 + l15), bytes [k + quad*16, +16)
  const int8_t* Wb = W + (size_t)(n0 + wn * 64 + l15) * ND + quad * 16;

  v4i acc[4][4];
  const v4i vzero = {0, 0, 0, 0};
  #pragma unroll
  for (int i = 0; i < 4; ++i)
    #pragma unroll
    for (int j = 0; j < 4; ++j) acc[i][j] = vzero;

  v4i bcur[4], bnxt[4];
  // prologue: stage A(k=0) into buf 0; load B(k=0)
  gl2lds16(Xa0, lA0[0]);
  gl2lds16(Xa1, lA1[0]);
  #pragma unroll
  for (int nt = 0; nt < 4; ++nt) bcur[nt] = *(const v4i*)(Wb + (size_t)nt * 16 * ND);

  for (int k0 = 0; k0 < ND; k0 += 128) {
    // ---- half 0: compute k0 from As[0]/bcur; prefetch k0+64 ----
    __syncthreads();                       // As[0] ready; all readers of As[1] done
    gl2lds16(Xa0 + k0 + 64, lA0[1]);
    gl2lds16(Xa1 + k0 + 64, lA1[1]);
    #pragma unroll
    for (int nt = 0; nt < 4; ++nt) bnxt[nt] = *(const v4i*)(Wb + (size_t)nt * 16 * ND + k0 + 64);
    {
      v4i a[4];
      #pragma unroll
      for (int mt = 0; mt < 4; ++mt) a[mt] = *(const v4i*)&As[0][wm*64 + mt*16 + l15][rqcol];
      #pragma unroll
      for (int mt = 0; mt < 4; ++mt)
        #pragma unroll
        for (int nt = 0; nt < 4; ++nt)
          acc[mt][nt] = __builtin_amdgcn_mfma_i32_16x16x64_i8(a[mt], bcur[nt], acc[mt][nt], 0, 0, 0);
    }
    // ---- half 1: compute k0+64 from As[1]/bnxt; prefetch k0+128 ----
    __syncthreads();                       // As[1] ready; all readers of As[0] done
    if (k0 + 128 < ND) {
      gl2lds16(Xa0 + k0 + 128, lA0[0]);
      gl2lds16(Xa1 + k0 + 128, lA1[0]);
      #pragma unroll
      for (int nt = 0; nt < 4; ++nt) bcur[nt] = *(const v4i*)(Wb + (size_t)nt * 16 * ND + k0 + 128);
    }
    {
      v4i a[4];
      #pragma unroll
      for (int mt = 0; mt < 4; ++mt) a[mt] = *(const v4i*)&As[1][wm*64 + mt*16 + l15][rqcol];
      #pragma unroll
      for (int mt = 0; mt < 4; ++mt)
        #pragma unroll
        for (int nt = 0; nt < 4; ++nt)
          acc[mt][nt] = __builtin_amdgcn_mfma_i32_16x16x64_i8(a[mt], bnxt[nt], acc[mt][nt], 0, 0, 0);
    }
  }

  float bf[4];
  #pragma unroll
  for (int nt = 0; nt < 4; ++nt) bf[nt] = (float)bias[n0 + wn*64 + nt*16 + l15];

  if (z == 2) {
    // Vt[b][h][hd][t]: t = m-dir; quad*4+r are 4 consecutive t -> pack u32
    #pragma unroll
    for (int mt = 0; mt < 4; ++mt)
      #pragma unroll
      for (int nt = 0; nt < 4; ++nt) {
        int tbase = (m0 + wm*64 + mt*16 + quad*4) & (NT - 1);
        int bb = (m0 + wm*64) >> 11;
        int n = n0 + wn*64 + nt*16 + l15;
        int hh = n >> 6, hd = n & (NHD - 1);
        uint32_t pk = 0;
        #pragma unroll
        for (int r = 0; r < 4; ++r) {
          uint32_t q = (uint32_t)(uint8_t)sat8(A_PROJ * (float)acc[mt][nt][r] + bf[nt]);
          pk |= q << (8 * r);
        }
        size_t bh = (size_t)bb * NH + hh;
        *(uint32_t*)&Vt[(bh * NHD + hd) * NT + tbase] = pk;
      }
  } else {
    int8_t* O = (z == 0) ? Qh : Kh;
    #pragma unroll
    for (int mt = 0; mt < 4; ++mt)
      #pragma unroll
      for (int nt = 0; nt < 4; ++nt)
        #pragma unroll
        for (int r = 0; r < 4; ++r) {
          int m = m0 + wm*64 + mt*16 + quad*4 + r;
          int n = n0 + wn*64 + nt*16 + l15;
          int8_t q = sat8(A_PROJ * (float)acc[mt][nt][r] + bf[nt]);
          int bb = m >> 11, t = m & (NT - 1);
          int hh = n >> 6, hd = n & (NHD - 1);
          size_t bh = (size_t)bb * NH + hh;
          O[(bh * NT + t) * NHD + hd] = q;
        }
  }
}

// ---------------- fused causal attention (v3, unchanged from R5) ----------------
__global__ __launch_bounds__(256) void attn_fused(
    const int8_t* __restrict__ Qh, const int8_t* __restrict__ Kh, const int8_t* __restrict__ Vt,
    int8_t* __restrict__ AO)
{
  __shared__ __align__(16) int8_t Ks[128][64];        // stored chunk = logical ^ ((row>>1)&3)
  __shared__ __align__(16) int8_t Vs[64][128];        // stored chunk = logical ^ (row&7)
  __shared__ __align__(16) uint32_t Ps32[4][16][36];  // per-wave P (u32-packed, +pad)

  const int bx = blockIdx.x;
  const int bh = blockIdx.y;
  const int tid = threadIdx.x, lane = tid & 63, wave = tid >> 6;
  const int l15 = lane & 15, quad = lane >> 4;
  const v4i vzero = {0, 0, 0, 0};
  const float MAGIC = 12582912.0f;    // 1.5*2^23: low byte of fmaf(e,linv,MAGIC) = rne(e*linv)
  const float C2 = 2.8853900817779268e-05f;  // A_QK * log2(e): exp(A_QK x) = exp2(C2 x)

  const int8_t* Qp = Qh + (size_t)bh * NT * NHD;
  const int8_t* Kp = Kh + (size_t)bh * NT * NHD;
  const int8_t* Vp = Vt + (size_t)bh * NHD * NT;
  const int bb = bh >> 5, hhead = bh & (NH - 1);

  const int kst_row = lane >> 2;
  const int kst_col = (((lane & 3) ^ ((lane >> 3) & 3)) * 16);
  const int vst_row = lane >> 3;
  const int vst_col = (((lane & 7) ^ ((lane >> 3) & 7)) * 16);
  const int kfcol = (quad ^ ((l15 >> 1) & 3)) * 16;

  for (int half = 0; half < 2; ++half) {
    const int xq = half ? (31 - bx) : bx;
    const int t0 = xq * 64;
    const int sd = xq >> 1;              // diagonal s-tile index (128-wide s-tiles)
    const int tme = t0 + wave * 16 + l15;

    v4i qf = *(const v4i*)&Qp[(size_t)(t0 + wave * 16 + l15) * NHD + quad * 16];

    // ---- pass 1: l = sum_s exp(score); bounded scores -> no max subtraction
    float lsum = 0.f;
    for (int st = 0; st <= sd; ++st) {
      const int s0 = st * 128;
      #pragma unroll
      for (int j = 0; j < 2; ++j)
        gl2lds16(&Kp[(size_t)(s0 + j*64 + wave*16 + kst_row) * NHD + kst_col],
                 &Ks[j*64 + wave*16][0]);
      __syncthreads();
      v4i kf[8];
      #pragma unroll
      for (int mt = 0; mt < 8; ++mt) kf[mt] = *(const v4i*)&Ks[mt*16 + l15][kfcol];
      if (st < sd) {
        #pragma unroll
        for (int mt = 0; mt < 8; ++mt) {
          v4i sa = __builtin_amdgcn_mfma_i32_16x16x64_i8(kf[mt], qf, vzero, 0, 0, 0);
          #pragma unroll
          for (int r = 0; r < 4; ++r) lsum += exp2_fast(C2 * (float)sa[r]);
        }
      } else {
        #pragma unroll
        for (int mt = 0; mt < 8; ++mt) {
          v4i sa = __builtin_amdgcn_mfma_i32_16x16x64_i8(kf[mt], qf, vzero, 0, 0, 0);
          const int sbase = s0 + mt*16 + quad*4;
          #pragma unroll
          for (int r = 0; r < 4; ++r) {
            float e = exp2_fast(C2 * (float)sa[r]);
            lsum += (sbase + r <= tme) ? e : 0.f;
          }
        }
      }
      __syncthreads();
    }
    {
      lsum += __shfl_xor(lsum, 16, 64);   // reduce over quads (same l15 = same t)
      lsum += __shfl_xor(lsum, 32, 64);
    }
    const float linv = 127.0f / lsum;

    // ---- pass 2: p_i8 = rne(127*e/l) via magic trick; PV int8 MFMA accumulate
    v4i accv[4];
    #pragma unroll
    for (int j = 0; j < 4; ++j) accv[j] = vzero;

    for (int st = 0; st <= sd; ++st) {
      const int s0 = st * 128;
      #pragma unroll
      for (int j = 0; j < 2; ++j)
        gl2lds16(&Kp[(size_t)(s0 + j*64 + wave*16 + kst_row) * NHD + kst_col],
                 &Ks[j*64 + wave*16][0]);
      #pragma unroll
      for (int j = 0; j < 2; ++j)
        gl2lds16(&Vp[(size_t)(j*32 + wave*8 + vst_row) * NT + s0 + vst_col],
                 &Vs[j*32 + wave*8][0]);
      __syncthreads();
      v4i kf[8];
      #pragma unroll
      for (int mt = 0; mt < 8; ++mt) kf[mt] = *(const v4i*)&Ks[mt*16 + l15][kfcol];

      if (st < sd) {
        #pragma unroll
        for (int mt = 0; mt < 8; ++mt) {
          v4i sa = __builtin_amdgcn_mfma_i32_16x16x64_i8(kf[mt], qf, vzero, 0, 0, 0);
          uint32_t pk = 0;
          #pragma unroll
          for (int r = 0; r < 4; ++r) {
            float e = exp2_fast(C2 * (float)sa[r]);
            float f = fmaf(e, linv, MAGIC);
            pk |= (__float_as_uint(f) & 0xFFu) << (8 * r);
          }
          Ps32[wave][l15][mt*4 + quad] = pk;
        }
      } else {
        #pragma unroll
        for (int mt = 0; mt < 8; ++mt) {
          v4i sa = __builtin_amdgcn_mfma_i32_16x16x64_i8(kf[mt], qf, vzero, 0, 0, 0);
          uint32_t pk = 0;
          const int sbase = s0 + mt*16 + quad*4;
          #pragma unroll
          for (int r = 0; r < 4; ++r) {
            float e = (sbase + r <= tme) ? exp2_fast(C2 * (float)sa[r]) : 0.f;
            float f = fmaf(e, linv, MAGIC);
            pk |= (__float_as_uint(f) & 0xFFu) << (8 * r);
          }
          Ps32[wave][l15][mt*4 + quad] = pk;
        }
      }
      // wave-private LDS RAW: same-wave DS ordering + compiler lgkmcnt — no barrier
      #pragma unroll
      for (int ks = 0; ks < 2; ++ks) {
        v4i ap = *(const v4i*)&Ps32[wave][l15][ks*16 + quad*4];
        #pragma unroll
        for (int nt2 = 0; nt2 < 4; ++nt2) {
          v4i bv = *(const v4i*)&Vs[nt2*16 + l15][(((ks*4 + quad) ^ (l15 & 7)) * 16)];
          accv[nt2] = __builtin_amdgcn_mfma_i32_16x16x64_i8(ap, bv, accv[nt2], 0, 0, 0);
        }
      }
      __syncthreads();
    }

    // epilogue: AO[b][t][h*64+d];  C/D: row(quad*4+r)=t-local, col(l15)=d-local
    #pragma unroll
    for (int nt2 = 0; nt2 < 4; ++nt2)
      #pragma unroll
      for (int r = 0; r < 4; ++r) {
        int t = t0 + wave*16 + quad*4 + r;
        int d = nt2*16 + l15;
        AO[((size_t)bb * NT + t) * ND + hhead * NHD + d] = sat8(A_PV * (float)accv[nt2][r]);
      }
  }
}

// ---------------- out projection (B-direct restructured K-loop) ----------------
__global__ __launch_bounds__(256, 3) void gemm_out(
    const int8_t* __restrict__ X, const int8_t* __restrict__ W,
    const float* __restrict__ bo, float* __restrict__ out)
{
  __shared__ __align__(16) int8_t As[2][128][64];
  const int m0 = blockIdx.x * 128, n0 = blockIdx.y * 128;
  const int tid = threadIdx.x, lane = tid & 63, wave = tid >> 6;
  const int wm = wave >> 1, wn = wave & 1;
  const int l15 = lane & 15, quad = lane >> 4;
  const int srow = lane >> 2;
  const int scol = (((lane & 3) ^ ((lane >> 3) & 3)) * 16);
  const int rqcol = (quad ^ ((l15 >> 1) & 3)) * 16;

  const int8_t* Xa0 = X + (size_t)(m0 + wave * 16 + srow) * ND + scol;
  const int8_t* Xa1 = X + (size_t)(m0 + (wave + 4) * 16 + srow) * ND + scol;
  int8_t* lA0[2] = { &As[0][wave * 16][0], &As[1][wave * 16][0] };
  int8_t* lA1[2] = { &As[0][(wave + 4) * 16][0], &As[1][(wave + 4) * 16][0] };
  const int8_t* Wb = W + (size_t)(n0 + wn * 64 + l15) * ND + quad * 16;

  v4i acc[4][4];
  const v4i vzero = {0, 0, 0, 0};
  #pragma unroll
  for (int i = 0; i < 4; ++i)
    #pragma unroll
    for (int j = 0; j < 4; ++j) acc[i][j] = vzero;

  v4i bcur[4], bnxt[4];
  gl2lds16(Xa0, lA0[0]);
  gl2lds16(Xa1, lA1[0]);
  #pragma unroll
  for (int nt = 0; nt < 4; ++nt) bcur[nt] = *(const v4i*)(Wb + (size_t)nt * 16 * ND);

  for (int k0 = 0; k0 < ND; k0 += 128) {
    __syncthreads();
    gl2lds16(Xa0 + k0 + 64, lA0[1]);
    gl2lds16(Xa1 + k0 + 64, lA1[1]);
    #pragma unroll
    for (int nt = 0; nt < 4; ++nt) bnxt[nt] = *(const v4i*)(Wb + (size_t)nt * 16 * ND + k0 + 64);
    {
      v4i a[4];
      #pragma unroll
      for (int mt = 0; mt < 4; ++mt) a[mt] = *(const v4i*)&As[0][wm*64 + mt*16 + l15][rqcol];
      #pragma unroll
      for (int mt = 0; mt < 4; ++mt)
        #pragma unroll
        for (int nt = 0; nt < 4; ++nt)
          acc[mt][nt] = __builtin_amdgcn_mfma_i32_16x16x64_i8(a[mt], bcur[nt], acc[mt][nt], 0, 0, 0);
    }
    __syncthreads();
    if (k0 + 128 < ND) {
      gl2lds16(Xa0 + k0 + 128, lA0[0]);
      gl2lds16(Xa1 + k0 + 128, lA1[0]);
      #pragma unroll
      for (int nt = 0; nt < 4; ++nt) bcur[nt] = *(const v4i*)(Wb + (size_t)nt * 16 * ND + k0 + 128);
    }
    {
      v4i a[4];
      #pragma unroll
      for (int mt = 0; mt < 4; ++mt) a[mt] = *(const v4i*)&As[1][wm*64 + mt*16 + l15][rqcol];
      #pragma unroll
      for (int mt = 0; mt < 4; ++mt)
        #pragma unroll
        for (int nt = 0; nt < 4; ++nt)
          acc[mt][nt] = __builtin_amdgcn_mfma_i32_16x16x64_i8(a[mt], bnxt[nt], acc[mt][nt], 0, 0, 0);
    }
  }

  float bf[4];
  #pragma unroll
  for (int nt = 0; nt < 4; ++nt) bf[nt] = bo[n0 + wn*64 + nt*16 + l15];

  #pragma unroll
  for (int mt = 0; mt < 4; ++mt)
    #pragma unroll
    for (int nt = 0; nt < 4; ++nt)
      #pragma unroll
      for (int r = 0; r < 4; ++r) {
        int m = m0 + wm*64 + mt*16 + quad*4 + r;
        int n = n0 + wn*64 + nt*16 + l15;
        out[(size_t)m * ND + n] = A_OUT * (float)acc[mt][nt][r] + bf[nt];
      }
}

extern "C" void kernel_launch(void* const* d_in, const int* in_sizes, int n_in,
                              void* d_out, int out_size, void* d_ws, size_t ws_size,
                              hipStream_t stream)
{
  const int*   hs  = (const int*)d_in[0];
  // d_in[1] = attention_mask: causal triu(-1e9) — applied structurally (s>t => p=0)
  const int*   Wq  = (const int*)d_in[2];
  const int*   bq  = (const int*)d_in[3];
  const int*   Wk  = (const int*)d_in[4];
  const int*   bkb = (const int*)d_in[5];
  const int*   Wv  = (const int*)d_in[6];
  const int*   bvb = (const int*)d_in[7];
  const int*   Wo  = (const int*)d_in[8];
  const float* bo  = (const float*)d_in[9];
  float* out = (float*)d_out;

  char* ws = (char*)d_ws;
  const size_t SZ_X = (size_t)NM * ND;              // 8 MiB
  const size_t SZ_W = (size_t)ND * ND;              // 4 MiB
  const size_t SZ_H = (size_t)NB * NH * NT * NHD;   // 8 MiB
  int8_t* Xp  = (int8_t*)ws;           // reused as AO after qkv gemm completes
  int8_t* Wqp = (int8_t*)(ws + SZ_X);
  int8_t* Wkp = Wqp + SZ_W;
  int8_t* Wvp = Wkp + SZ_W;
  int8_t* Wop = Wvp + SZ_W;
  int8_t* Qh  = Wop + SZ_W;
  int8_t* Kh  = Qh + SZ_H;
  int8_t* Vt  = Kh + SZ_H;
  int8_t* AO  = Xp;                    // alias: total ws use ~50.4 MB

  const int ntot = (int)(SZ_X/4 + 4 * (SZ_W/4));
  pack_all<<<(ntot + 255) / 256, 256, 0, stream>>>(hs, Wq, Wk, Wv, Wo,
                                                   Xp, Wqp, Wkp, Wvp, Wop);

  gemm_qkv<<<dim3(NM/128, ND/128, 3), 256, 0, stream>>>(Xp, Wqp, Wkp, Wvp, bq, bkb, bvb, Qh, Kh, Vt);
  attn_fused<<<dim3(16, NB*NH), 256, 0, stream>>>(Qh, Kh, Vt, AO);
  gemm_out<<<dim3(NM/128, ND/128), 256, 0, stream>>>(AO, Wop, bo, out);
}

// Round 7
// 328.722 us; speedup vs baseline: 1.1840x; 1.1840x over previous
//
#include <hip/hip_runtime.h>
#include <cstdint>

// Int8 OPT attention block: B=2,T=2048,D=2048,H=32,HD=64
#define A_PROJ 3e-4f
#define A_QK   2e-5f
#define A_PV   1e-2f
#define A_OUT  1e-4f

#define NB 2
#define NT 2048
#define ND 2048
#define NH 32
#define NHD 64
#define NM (NB*NT)   // 4096 = B*T rows

typedef int v4i __attribute__((ext_vector_type(4)));

__device__ __forceinline__ int8_t sat8(float y) {
  float r = rintf(y);                      // half-to-even == np.round
  r = fminf(fmaxf(r, -128.f), 127.f);
  return (int8_t)(int)r;
}

// raw v_exp_f32: D = 2^x (device builtin; __exp2f collides with glibc macros)
__device__ __forceinline__ float exp2_fast(float x) {
  return __builtin_amdgcn_exp2f(x);
}

// async global->LDS, 16B/lane; LDS dest = wave-uniform base + lane*16
__device__ __forceinline__ void gl2lds16(const int8_t* g, int8_t* l) {
  __builtin_amdgcn_global_load_lds(
      (const __attribute__((address_space(1))) void*)g,
      (__attribute__((address_space(3))) void*)l, 16, 0, 0);
}

// ---------------- fused pack: int32 -> int8 for X + 4 weights ----------------
#define NWW (ND*ND/4)      // 1048576 words = 2^20
__global__ void pack_all(const int* __restrict__ X,
                         const int* __restrict__ W0, const int* __restrict__ W1,
                         const int* __restrict__ W2, const int* __restrict__ W3,
                         int8_t* __restrict__ dX, int8_t* __restrict__ dW0,
                         int8_t* __restrict__ dW1, int8_t* __restrict__ dW2,
                         int8_t* __restrict__ dW3) {
  int i = blockIdx.x * blockDim.x + threadIdx.x;
  const int nx = NM*ND/4;
  const int* src; int8_t* dst; int off;
  if (i < nx) { src = X; dst = dX; off = i; }
  else {
    int j = i - nx;
    int r = j >> 20;            // NWW = 2^20
    off = j & (NWW - 1);
    src = (r == 0) ? W0 : (r == 1) ? W1 : (r == 2) ? W2 : W3;
    dst = (r == 0) ? dW0 : (r == 1) ? dW1 : (r == 2) ? dW2 : dW3;
  }
  int4 v = ((const int4*)src)[off];
  uint32_t p = (uint32_t)(v.x & 255) | ((uint32_t)(v.y & 255) << 8) |
               ((uint32_t)(v.z & 255) << 16) | ((uint32_t)(v.w & 255) << 24);
  ((uint32_t*)dst)[off] = p;
}

// ---------------- QKV projection: C = sat8(A_PROJ * X @ W^T + bias) ----------------
// R5 structure (measured 87.4 us, SQ_LDS_BANK_CONFLICT=0): gl2lds16 staging of
// A and B, BK=128 as two 64-col halves, chunk-XOR swizzle, 2 barriers/iter.
// R6's barrier-drain restructure regressed (vmcnt(0) drains B loads too) -> reverted.
// z=0 -> Qh[b][h][t][hd], z=1 -> Kh[b][h][t][hd], z=2 -> Vt[b][h][hd][t] (u32-packed store)
__global__ __launch_bounds__(256) void gemm_qkv(
    const int8_t* __restrict__ X,
    const int8_t* __restrict__ Wq, const int8_t* __restrict__ Wk, const int8_t* __restrict__ Wv,
    const int* __restrict__ bq, const int* __restrict__ bk, const int* __restrict__ bv,
    int8_t* __restrict__ Qh, int8_t* __restrict__ Kh, int8_t* __restrict__ Vt)
{
  __shared__ __align__(16) int8_t As[2][128][64];   // stored chunk = logical ^ ((row>>1)&3)
  __shared__ __align__(16) int8_t Bs[2][128][64];
  const int z = blockIdx.z;
  const int8_t* W  = (z == 0) ? Wq : ((z == 1) ? Wk : Wv);
  const int* bias  = (z == 0) ? bq : ((z == 1) ? bk : bv);
  const int m0 = blockIdx.x * 128, n0 = blockIdx.y * 128;
  const int tid = threadIdx.x, lane = tid & 63, wave = tid >> 6;
  const int wm = wave >> 1, wn = wave & 1;
  const int l15 = lane & 15, quad = lane >> 4;

  const int srow = lane >> 2;                               // staging row within 16-block
  const int scol = (((lane & 3) ^ ((lane >> 3) & 3)) * 16); // swizzled logical chunk
  const int rqcol = (quad ^ ((l15 >> 1) & 3)) * 16;         // frag-read stored chunk

  v4i acc[4][4];
  const v4i vzero = {0, 0, 0, 0};
  #pragma unroll
  for (int i = 0; i < 4; ++i)
    #pragma unroll
    for (int j = 0; j < 4; ++j) acc[i][j] = vzero;

  for (int k0 = 0; k0 < ND; k0 += 128) {
    #pragma unroll
    for (int j = 0; j < 8; ++j) {
      int slot = j * 4 + wave;
      int sl = slot & 15;
      int hh = sl >> 3, rblk = sl & 7;
      int row = rblk * 16 + srow;
      if (slot < 16) {
        gl2lds16(&X[(size_t)(m0 + row) * ND + k0 + hh * 64 + scol], &As[hh][rblk * 16][0]);
      } else {
        gl2lds16(&W[(size_t)(n0 + row) * ND + k0 + hh * 64 + scol], &Bs[hh][rblk * 16][0]);
      }
    }
    __syncthreads();
    #pragma unroll
    for (int hh = 0; hh < 2; ++hh) {
      v4i a[4], b[4];
      #pragma unroll
      for (int mt = 0; mt < 4; ++mt) a[mt] = *(const v4i*)&As[hh][wm*64 + mt*16 + l15][rqcol];
      #pragma unroll
      for (int nt = 0; nt < 4; ++nt) b[nt] = *(const v4i*)&Bs[hh][wn*64 + nt*16 + l15][rqcol];
      #pragma unroll
      for (int mt = 0; mt < 4; ++mt)
        #pragma unroll
        for (int nt = 0; nt < 4; ++nt)
          acc[mt][nt] = __builtin_amdgcn_mfma_i32_16x16x64_i8(a[mt], b[nt], acc[mt][nt], 0, 0, 0);
    }
    __syncthreads();
  }

  float bf[4];
  #pragma unroll
  for (int nt = 0; nt < 4; ++nt) bf[nt] = (float)bias[n0 + wn*64 + nt*16 + l15];

  if (z == 2) {
    // Vt[b][h][hd][t]: t = m-dir; quad*4+r are 4 consecutive t -> pack u32
    #pragma unroll
    for (int mt = 0; mt < 4; ++mt)
      #pragma unroll
      for (int nt = 0; nt < 4; ++nt) {
        int tbase = (m0 + wm*64 + mt*16 + quad*4) & (NT - 1);
        int bb = (m0 + wm*64) >> 11;
        int n = n0 + wn*64 + nt*16 + l15;
        int hh = n >> 6, hd = n & (NHD - 1);
        uint32_t pk = 0;
        #pragma unroll
        for (int r = 0; r < 4; ++r) {
          uint32_t q = (uint32_t)(uint8_t)sat8(A_PROJ * (float)acc[mt][nt][r] + bf[nt]);
          pk |= q << (8 * r);
        }
        size_t bh = (size_t)bb * NH + hh;
        *(uint32_t*)&Vt[(bh * NHD + hd) * NT + tbase] = pk;
      }
  } else {
    int8_t* O = (z == 0) ? Qh : Kh;
    #pragma unroll
    for (int mt = 0; mt < 4; ++mt)
      #pragma unroll
      for (int nt = 0; nt < 4; ++nt)
        #pragma unroll
        for (int r = 0; r < 4; ++r) {
          int m = m0 + wm*64 + mt*16 + quad*4 + r;     // C/D: row = quad*4+reg
          int n = n0 + wn*64 + nt*16 + l15;            //      col = lane&15
          int8_t q = sat8(A_PROJ * (float)acc[mt][nt][r] + bf[nt]);
          int bb = m >> 11, t = m & (NT - 1);
          int hh = n >> 6, hd = n & (NHD - 1);
          size_t bh = (size_t)bb * NH + hh;
          O[(bh * NT + t) * NHD + hd] = q;
        }
  }
}

// ---------------- fused causal attention (v3, unchanged) ----------------
// 64-row q-subtiles, triangle-paired (bx, 31-bx); 4 waves x 16 q-rows.
// gl2lds16 staging for K/V with chunk-XOR swizzle; Q frags direct from global.
// S^T orientation: A=K (m=s), B=Q (n=t); exp via exp2 fold.
__global__ __launch_bounds__(256) void attn_fused(
    const int8_t* __restrict__ Qh, const int8_t* __restrict__ Kh, const int8_t* __restrict__ Vt,
    int8_t* __restrict__ AO)
{
  __shared__ __align__(16) int8_t Ks[128][64];        // stored chunk = logical ^ ((row>>1)&3)
  __shared__ __align__(16) int8_t Vs[64][128];        // stored chunk = logical ^ (row&7)
  __shared__ __align__(16) uint32_t Ps32[4][16][36];  // per-wave P (u32-packed, +pad)

  const int bx = blockIdx.x;
  const int bh = blockIdx.y;
  const int tid = threadIdx.x, lane = tid & 63, wave = tid >> 6;
  const int l15 = lane & 15, quad = lane >> 4;
  const v4i vzero = {0, 0, 0, 0};
  const float MAGIC = 12582912.0f;    // 1.5*2^23: low byte of fmaf(e,linv,MAGIC) = rne(e*linv)
  const float C2 = 2.8853900817779268e-05f;  // A_QK * log2(e): exp(A_QK x) = exp2(C2 x)

  const int8_t* Qp = Qh + (size_t)bh * NT * NHD;
  const int8_t* Kp = Kh + (size_t)bh * NT * NHD;
  const int8_t* Vp = Vt + (size_t)bh * NHD * NT;
  const int bb = bh >> 5, hhead = bh & (NH - 1);

  const int kst_row = lane >> 2;
  const int kst_col = (((lane & 3) ^ ((lane >> 3) & 3)) * 16);
  const int vst_row = lane >> 3;
  const int vst_col = (((lane & 7) ^ ((lane >> 3) & 7)) * 16);
  const int kfcol = (quad ^ ((l15 >> 1) & 3)) * 16;

  for (int half = 0; half < 2; ++half) {
    const int xq = half ? (31 - bx) : bx;
    const int t0 = xq * 64;
    const int sd = xq >> 1;              // diagonal s-tile index (128-wide s-tiles)
    const int tme = t0 + wave * 16 + l15;

    v4i qf = *(const v4i*)&Qp[(size_t)(t0 + wave * 16 + l15) * NHD + quad * 16];

    // ---- pass 1: l = sum_s exp(score); bounded scores -> no max subtraction
    float lsum = 0.f;
    for (int st = 0; st <= sd; ++st) {
      const int s0 = st * 128;
      #pragma unroll
      for (int j = 0; j < 2; ++j)
        gl2lds16(&Kp[(size_t)(s0 + j*64 + wave*16 + kst_row) * NHD + kst_col],
                 &Ks[j*64 + wave*16][0]);
      __syncthreads();
      v4i kf[8];
      #pragma unroll
      for (int mt = 0; mt < 8; ++mt) kf[mt] = *(const v4i*)&Ks[mt*16 + l15][kfcol];
      if (st < sd) {
        #pragma unroll
        for (int mt = 0; mt < 8; ++mt) {
          v4i sa = __builtin_amdgcn_mfma_i32_16x16x64_i8(kf[mt], qf, vzero, 0, 0, 0);
          #pragma unroll
          for (int r = 0; r < 4; ++r) lsum += exp2_fast(C2 * (float)sa[r]);
        }
      } else {
        #pragma unroll
        for (int mt = 0; mt < 8; ++mt) {
          v4i sa = __builtin_amdgcn_mfma_i32_16x16x64_i8(kf[mt], qf, vzero, 0, 0, 0);
          const int sbase = s0 + mt*16 + quad*4;
          #pragma unroll
          for (int r = 0; r < 4; ++r) {
            float e = exp2_fast(C2 * (float)sa[r]);
            lsum += (sbase + r <= tme) ? e : 0.f;
          }
        }
      }
      __syncthreads();
    }
    {
      lsum += __shfl_xor(lsum, 16, 64);   // reduce over quads (same l15 = same t)
      lsum += __shfl_xor(lsum, 32, 64);
    }
    const float linv = 127.0f / lsum;

    // ---- pass 2: p_i8 = rne(127*e/l) via magic trick; PV int8 MFMA accumulate
    v4i accv[4];
    #pragma unroll
    for (int j = 0; j < 4; ++j) accv[j] = vzero;

    for (int st = 0; st <= sd; ++st) {
      const int s0 = st * 128;
      #pragma unroll
      for (int j = 0; j < 2; ++j)
        gl2lds16(&Kp[(size_t)(s0 + j*64 + wave*16 + kst_row) * NHD + kst_col],
                 &Ks[j*64 + wave*16][0]);
      #pragma unroll
      for (int j = 0; j < 2; ++j)
        gl2lds16(&Vp[(size_t)(j*32 + wave*8 + vst_row) * NT + s0 + vst_col],
                 &Vs[j*32 + wave*8][0]);
      __syncthreads();
      v4i kf[8];
      #pragma unroll
      for (int mt = 0; mt < 8; ++mt) kf[mt] = *(const v4i*)&Ks[mt*16 + l15][kfcol];

      if (st < sd) {
        #pragma unroll
        for (int mt = 0; mt < 8; ++mt) {
          v4i sa = __builtin_amdgcn_mfma_i32_16x16x64_i8(kf[mt], qf, vzero, 0, 0, 0);
          uint32_t pk = 0;
          #pragma unroll
          for (int r = 0; r < 4; ++r) {
            float e = exp2_fast(C2 * (float)sa[r]);
            float f = fmaf(e, linv, MAGIC);
            pk |= (__float_as_uint(f) & 0xFFu) << (8 * r);
          }
          Ps32[wave][l15][mt*4 + quad] = pk;
        }
      } else {
        #pragma unroll
        for (int mt = 0; mt < 8; ++mt) {
          v4i sa = __builtin_amdgcn_mfma_i32_16x16x64_i8(kf[mt], qf, vzero, 0, 0, 0);
          uint32_t pk = 0;
          const int sbase = s0 + mt*16 + quad*4;
          #pragma unroll
          for (int r = 0; r < 4; ++r) {
            float e = (sbase + r <= tme) ? exp2_fast(C2 * (float)sa[r]) : 0.f;
            float f = fmaf(e, linv, MAGIC);
            pk |= (__float_as_uint(f) & 0xFFu) << (8 * r);
          }
          Ps32[wave][l15][mt*4 + quad] = pk;
        }
      }
      // wave-private LDS RAW: same-wave DS ordering + compiler lgkmcnt — no barrier
      #pragma unroll
      for (int ks = 0; ks < 2; ++ks) {
        v4i ap = *(const v4i*)&Ps32[wave][l15][ks*16 + quad*4];
        #pragma unroll
        for (int nt2 = 0; nt2 < 4; ++nt2) {
          v4i bv = *(const v4i*)&Vs[nt2*16 + l15][(((ks*4 + quad) ^ (l15 & 7)) * 16)];
          accv[nt2] = __builtin_amdgcn_mfma_i32_16x16x64_i8(ap, bv, accv[nt2], 0, 0, 0);
        }
      }
      __syncthreads();
    }

    // epilogue: AO[b][t][h*64+d];  C/D: row(quad*4+r)=t-local, col(l15)=d-local
    #pragma unroll
    for (int nt2 = 0; nt2 < 4; ++nt2)
      #pragma unroll
      for (int r = 0; r < 4; ++r) {
        int t = t0 + wave*16 + quad*4 + r;
        int d = nt2*16 + l15;
        AO[((size_t)bb * NT + t) * ND + hhead * NHD + d] = sat8(A_PV * (float)accv[nt2][r]);
      }
  }
}

// ---------------- out projection: out = A_OUT * AO @ Wo^T + bo (fp32) ----------------
// R5 structure (reverted from R6).
__global__ __launch_bounds__(256) void gemm_out(
    const int8_t* __restrict__ X, const int8_t* __restrict__ W,
    const float* __restrict__ bo, float* __restrict__ out)
{
  __shared__ __align__(16) int8_t As[2][128][64];
  __shared__ __align__(16) int8_t Bs[2][128][64];
  const int m0 = blockIdx.x * 128, n0 = blockIdx.y * 128;
  const int tid = threadIdx.x, lane = tid & 63, wave = tid >> 6;
  const int wm = wave >> 1, wn = wave & 1;
  const int l15 = lane & 15, quad = lane >> 4;
  const int srow = lane >> 2;
  const int scol = (((lane & 3) ^ ((lane >> 3) & 3)) * 16);
  const int rqcol = (quad ^ ((l15 >> 1) & 3)) * 16;

  v4i acc[4][4];
  const v4i vzero = {0, 0, 0, 0};
  #pragma unroll
  for (int i = 0; i < 4; ++i)
    #pragma unroll
    for (int j = 0; j < 4; ++j) acc[i][j] = vzero;

  for (int k0 = 0; k0 < ND; k0 += 128) {
    #pragma unroll
    for (int j = 0; j < 8; ++j) {
      int slot = j * 4 + wave;
      int sl = slot & 15;
      int hh = sl >> 3, rblk = sl & 7;
      int row = rblk * 16 + srow;
      if (slot < 16) {
        gl2lds16(&X[(size_t)(m0 + row) * ND + k0 + hh * 64 + scol], &As[hh][rblk * 16][0]);
      } else {
        gl2lds16(&W[(size_t)(n0 + row) * ND + k0 + hh * 64 + scol], &Bs[hh][rblk * 16][0]);
      }
    }
    __syncthreads();
    #pragma unroll
    for (int hh = 0; hh < 2; ++hh) {
      v4i a[4], b[4];
      #pragma unroll
      for (int mt = 0; mt < 4; ++mt) a[mt] = *(const v4i*)&As[hh][wm*64 + mt*16 + l15][rqcol];
      #pragma unroll
      for (int nt = 0; nt < 4; ++nt) b[nt] = *(const v4i*)&Bs[hh][wn*64 + nt*16 + l15][rqcol];
      #pragma unroll
      for (int mt = 0; mt < 4; ++mt)
        #pragma unroll
        for (int nt = 0; nt < 4; ++nt)
          acc[mt][nt] = __builtin_amdgcn_mfma_i32_16x16x64_i8(a[mt], b[nt], acc[mt][nt], 0, 0, 0);
    }
    __syncthreads();
  }

  float bf[4];
  #pragma unroll
  for (int nt = 0; nt < 4; ++nt) bf[nt] = bo[n0 + wn*64 + nt*16 + l15];

  #pragma unroll
  for (int mt = 0; mt < 4; ++mt)
    #pragma unroll
    for (int nt = 0; nt < 4; ++nt)
      #pragma unroll
      for (int r = 0; r < 4; ++r) {
        int m = m0 + wm*64 + mt*16 + quad*4 + r;
        int n = n0 + wn*64 + nt*16 + l15;
        out[(size_t)m * ND + n] = A_OUT * (float)acc[mt][nt][r] + bf[nt];
      }
}

extern "C" void kernel_launch(void* const* d_in, const int* in_sizes, int n_in,
                              void* d_out, int out_size, void* d_ws, size_t ws_size,
                              hipStream_t stream)
{
  const int*   hs  = (const int*)d_in[0];
  // d_in[1] = attention_mask: causal triu(-1e9) — applied structurally (s>t => p=0)
  const int*   Wq  = (const int*)d_in[2];
  const int*   bq  = (const int*)d_in[3];
  const int*   Wk  = (const int*)d_in[4];
  const int*   bkb = (const int*)d_in[5];
  const int*   Wv  = (const int*)d_in[6];
  const int*   bvb = (const int*)d_in[7];
  const int*   Wo  = (const int*)d_in[8];
  const float* bo  = (const float*)d_in[9];
  float* out = (float*)d_out;

  char* ws = (char*)d_ws;
  const size_t SZ_X = (size_t)NM * ND;              // 8 MiB
  const size_t SZ_W = (size_t)ND * ND;              // 4 MiB
  const size_t SZ_H = (size_t)NB * NH * NT * NHD;   // 8 MiB
  int8_t* Xp  = (int8_t*)ws;           // reused as AO after qkv gemm completes
  int8_t* Wqp = (int8_t*)(ws + SZ_X);
  int8_t* Wkp = Wqp + SZ_W;
  int8_t* Wvp = Wkp + SZ_W;
  int8_t* Wop = Wvp + SZ_W;
  int8_t* Qh  = Wop + SZ_W;
  int8_t* Kh  = Qh + SZ_H;
  int8_t* Vt  = Kh + SZ_H;
  int8_t* AO  = Xp;                    // alias: total ws use ~50.4 MB

  const int ntot = (int)(SZ_X/4 + 4 * (SZ_W/4));
  pack_all<<<(ntot + 255) / 256, 256, 0, stream>>>(hs, Wq, Wk, Wv, Wo,
                                                   Xp, Wqp, Wkp, Wvp, Wop);

  gemm_qkv<<<dim3(NM/128, ND/128, 3), 256, 0, stream>>>(Xp, Wqp, Wkp, Wvp, bq, bkb, bvb, Qh, Kh, Vt);
  attn_fused<<<dim3(16, NB*NH), 256, 0, stream>>>(Qh, Kh, Vt, AO);
  gemm_out<<<dim3(NM/128, ND/128), 256, 0, stream>>>(AO, Wop, bo, out);
}